// Round 1
// baseline (139.502 us; speedup 1.0000x reference)
//
#include <hip/hip_runtime.h>
#include <math.h>

#define NN 128
#define FF 32
#define TT 5

// ---------------------------------------------------------------------------
// Per-edge hoisted node-feature terms: wux[e,f] = sum_g W_u[e,f,g] * x[i,g]
// (e = i*N + j). One wave per (i,j); non-edges exit. Lane l: f = l>>1,
// g-half = l&1 (16 contiguous floats each -> coalesced 128B rows).
// ---------------------------------------------------------------------------
__global__ void k_wx(const int* __restrict__ adj, const float* __restrict__ x,
                     const float* __restrict__ Wu, const float* __restrict__ Wcm,
                     float* __restrict__ wux, float* __restrict__ wcmx) {
    const int e = blockIdx.x;
    if (!adj[e]) return;
    const int i = e >> 7;
    const int t = threadIdx.x;
    const int f = t >> 1, h = t & 1;
    __shared__ float xs[FF];
    if (t < FF) xs[t] = x[i * FF + t];
    __syncthreads();
    const size_t base = ((size_t)e * FF + f) * FF + h * 16;
    const float* __restrict__ wrow = Wu + base;
    const float* __restrict__ crow = Wcm + base;
    float a0 = 0.f, a1 = 0.f;
#pragma unroll
    for (int g = 0; g < 16; ++g) {
        const float xv = xs[h * 16 + g];
        a0 += wrow[g] * xv;
        a1 += crow[g] * xv;
    }
    a0 += __shfl_xor(a0, 1);
    a1 += __shfl_xor(a1, 1);
    if (h == 0) {
        wux[e * FF + f] = a0;
        wcmx[e * FF + f] = a1;
    }
}

// ---------------------------------------------------------------------------
// S_in[i,f] = sum_k M[k,i,f]  (column reduction over dense messages)
// ---------------------------------------------------------------------------
__global__ void k_sin(const float* __restrict__ M, float* __restrict__ SIN) {
    const int idx = blockIdx.x * blockDim.x + threadIdx.x;  // i*FF + f
    const int i = idx >> 5, f = idx & 31;
    float s = 0.f;
    for (int k = 0; k < NN; ++k) s += M[((size_t)k * NN + i) * FF + f];
    SIN[idx] = s;
}

// ---------------------------------------------------------------------------
// Per-edge phase 1: prev, z, r, rm.
//   prev[f] = SIN[i,f] - M[j,i,f]
//   z = sigmoid(wux + U_u@prev + b_u);  r = sigmoid(wux + U_u@m + b_u)
//   RM = r * m  (dense; non-edge entries stay 0 from the launch memset)
// ---------------------------------------------------------------------------
__global__ void k_p1(const int* __restrict__ adj, const float* __restrict__ Uu,
                     const float* __restrict__ bu, const float* __restrict__ wux,
                     const float* __restrict__ M, const float* __restrict__ SIN,
                     float* __restrict__ PREV, float* __restrict__ Z,
                     float* __restrict__ RM) {
    const int e = blockIdx.x;
    if (!adj[e]) return;
    const int i = e >> 7, j = e & 127;
    const int t = threadIdx.x;
    const int f = t >> 1, h = t & 1;
    __shared__ float prev_s[FF], m_s[FF];
    if (t < FF) {
        m_s[t] = M[(size_t)e * FF + t];
        prev_s[t] = SIN[i * FF + t] - M[((size_t)j * NN + i) * FF + t];
    }
    __syncthreads();
    const float* __restrict__ urow = Uu + ((size_t)e * FF + f) * FF + h * 16;
    float aP = 0.f, aM = 0.f;
#pragma unroll
    for (int g = 0; g < 16; ++g) {
        const float u = urow[g];
        aP += u * prev_s[h * 16 + g];
        aM += u * m_s[h * 16 + g];
    }
    aP += __shfl_xor(aP, 1);
    aM += __shfl_xor(aM, 1);
    if (h == 0) {
        const float wx = wux[e * FF + f] + bu[f];
        const float z = 1.f / (1.f + expf(-(wx + aP)));
        const float r = 1.f / (1.f + expf(-(wx + aM)));
        PREV[(size_t)e * FF + f] = prev_s[f];
        Z[(size_t)e * FF + f] = z;
        RM[(size_t)e * FF + f] = r * m_s[f];
    }
}

// ---------------------------------------------------------------------------
// R_out[i,f] = sum_j RM[i,j,f]  (row reduction)
// ---------------------------------------------------------------------------
__global__ void k_rout(const float* __restrict__ RM, float* __restrict__ ROUT) {
    const int idx = blockIdx.x * blockDim.x + threadIdx.x;  // i*FF + f
    const int i = idx >> 5, f = idx & 31;
    float s = 0.f;
    for (int j = 0; j < NN; ++j) s += RM[((size_t)i * NN + j) * FF + f];
    ROUT[idx] = s;
}

// ---------------------------------------------------------------------------
// Per-edge phase 2: reset_sum, cm, GRU compose -> new message (edges only).
// ---------------------------------------------------------------------------
__global__ void k_p3(const int* __restrict__ adj, const float* __restrict__ Ucm,
                     const float* __restrict__ bcm, const float* __restrict__ wcmx,
                     const float* __restrict__ ROUT, const float* __restrict__ RM,
                     const float* __restrict__ PREV, const float* __restrict__ Z,
                     float* __restrict__ M) {
    const int e = blockIdx.x;
    if (!adj[e]) return;
    const int i = e >> 7;
    const int t = threadIdx.x;
    const int f = t >> 1, h = t & 1;
    __shared__ float rs[FF];
    if (t < FF) rs[t] = ROUT[i * FF + t] - RM[(size_t)e * FF + t];
    __syncthreads();
    const float* __restrict__ urow = Ucm + ((size_t)e * FF + f) * FF + h * 16;
    float a = 0.f;
#pragma unroll
    for (int g = 0; g < 16; ++g) a += urow[g] * rs[h * 16 + g];
    a += __shfl_xor(a, 1);
    if (h == 0) {
        const float cm = tanhf(wcmx[(size_t)e * FF + f] + a + bcm[f]);
        const float z = Z[(size_t)e * FF + f];
        const float pv = PREV[(size_t)e * FF + f];
        M[(size_t)e * FF + f] = (1.f - z) * pv + z * cm;
    }
}

// ---------------------------------------------------------------------------
// Final: out_sum[i] = sum_j M[i,j]; enc = relu(U_nf[i]@x[i] + U_nm[i]@out_sum)
// ---------------------------------------------------------------------------
__global__ void k_final(const float* __restrict__ M, const float* __restrict__ x,
                        const float* __restrict__ Unf, const float* __restrict__ Unm,
                        float* __restrict__ out) {
    const int i = blockIdx.x;
    const int t = threadIdx.x;
    const int f = t >> 1, h = t & 1;
    __shared__ float os[FF], xs[FF];
    if (t < FF) {
        float s = 0.f;
        for (int j = 0; j < NN; ++j) s += M[((size_t)i * NN + j) * FF + t];
        os[t] = s;
        xs[t] = x[i * FF + t];
    }
    __syncthreads();
    const size_t base = ((size_t)i * FF + f) * FF + h * 16;
    const float* __restrict__ frow = Unf + base;
    const float* __restrict__ mrow = Unm + base;
    float a = 0.f;
#pragma unroll
    for (int g = 0; g < 16; ++g)
        a += frow[g] * xs[h * 16 + g] + mrow[g] * os[h * 16 + g];
    a += __shfl_xor(a, 1);
    if (h == 0) out[i * FF + f] = fmaxf(a, 0.f);
}

extern "C" void kernel_launch(void* const* d_in, const int* in_sizes, int n_in,
                              void* d_out, int out_size, void* d_ws, size_t ws_size,
                              hipStream_t stream) {
    const float* x   = (const float*)d_in[0];
    const int*   adj = (const int*)d_in[1];
    const float* Wu  = (const float*)d_in[2];
    const float* Uu  = (const float*)d_in[3];
    const float* Wcm = (const float*)d_in[4];
    const float* Ucm = (const float*)d_in[5];
    const float* bu  = (const float*)d_in[6];
    const float* bcm = (const float*)d_in[7];
    const float* Unf = (const float*)d_in[8];
    const float* Unm = (const float*)d_in[9];
    float* out = (float*)d_out;

    const size_t EF = (size_t)NN * NN * FF;  // 524288 floats per dense [N,N,F]
    float* p    = (float*)d_ws;
    float* M    = p; p += EF;
    float* RM   = p; p += EF;
    float* PREV = p; p += EF;
    float* Z    = p; p += EF;
    float* WUX  = p; p += EF;
    float* WCMX = p; p += EF;
    float* SIN  = p; p += (size_t)NN * FF;
    float* ROUT = p; p += (size_t)NN * FF;
    // total ws use: 6*2MiB + 32KiB = ~12.03 MiB

    // messages / rm must be zero on non-edges every call (reductions read dense)
    hipMemsetAsync(M, 0, EF * sizeof(float), stream);
    hipMemsetAsync(RM, 0, EF * sizeof(float), stream);

    k_wx<<<NN * NN, 64, 0, stream>>>(adj, x, Wu, Wcm, WUX, WCMX);
    for (int t = 0; t < TT; ++t) {
        k_sin<<<(NN * FF) / 256, 256, 0, stream>>>(M, SIN);
        k_p1<<<NN * NN, 64, 0, stream>>>(adj, Uu, bu, WUX, M, SIN, PREV, Z, RM);
        k_rout<<<(NN * FF) / 256, 256, 0, stream>>>(RM, ROUT);
        k_p3<<<NN * NN, 64, 0, stream>>>(adj, Ucm, bcm, WCMX, ROUT, RM, PREV, Z, M);
    }
    k_final<<<NN, 64, 0, stream>>>(M, x, Unf, Unm, out);
}